// Round 1
// baseline (376.330 us; speedup 1.0000x reference)
//
#include <hip/hip_runtime.h>
#include <hip/hip_bf16.h>

#define BS 8
#define S  32
#define L  128
#define D  768
#define P  496

typedef float  f32x4  __attribute__((ext_vector_type(4)));
typedef __bf16 bf16x8 __attribute__((ext_vector_type(8)));
typedef __bf16 bf16x4 __attribute__((ext_vector_type(4)));

// ---------------- K1: zero float4s ----------------
__global__ void k_zero(float4* __restrict__ p, int n) {
  int i = blockIdx.x * blockDim.x + threadIdx.x;
  if (i < n) p[i] = make_float4(0.f, 0.f, 0.f, 0.f);
}

// ---------------- K2: W1[d][h] f32 -> W1T[h][d] bf16 ----------------
__global__ void k_w1t(const float* __restrict__ w1, __bf16* __restrict__ w1t) {
  int idx = blockIdx.x * 256 + threadIdx.x;   // idx = h*D + d  (writes coalesced)
  int h = idx / D, d = idx - h * D;
  w1t[idx] = (__bf16)w1[d * D + h];
}

// ---------------- K3: scatter x_cls rows into cls output ----------------
__global__ void k_scatter(const float4* __restrict__ xcls, const int* __restrict__ pairs,
                          const int* __restrict__ pnum, float4* __restrict__ outc) {
  int p = blockIdx.x, b = blockIdx.y;
  if (p >= pnum[b]) return;
  int i = pairs[(b * P + p) * 2 + 0];
  int j = pairs[(b * P + p) * 2 + 1];
  const float4* src = xcls + (size_t)(b * P + p) * (D / 4);
  float4*       dst = outc + (size_t)((b * S + i) * S + j) * (D / 4);
  dst[threadIdx.x] = src[threadIdx.x];
}

// ---------------- K4: scores = w2 . tanh(x @ W1 + b1) ----------------
// Per WG: 64-row A panel resident in LDS (bf16, padded stride), loop n-tiles.
// 8 waves = 2 (M half) x 4 (N group). No barrier in K loop.
#define LDS_ROW_BYTES 1552                    // 768*2 + 16 pad (bank-uniform)
#define LDS_BYTES (64 * LDS_ROW_BYTES)        // 99328

__global__ __launch_bounds__(512, 1) void k_scores(
    const float* __restrict__ x, const __bf16* __restrict__ w1t,
    const float* __restrict__ b1, const float* __restrict__ w2,
    float* __restrict__ scores)
{
  extern __shared__ char smem[];
  const int tid = threadIdx.x;

  // ---- stage A: 64x768 f32 -> bf16 LDS (x read exactly once)
  const float4* x4 = reinterpret_cast<const float4*>(x + (size_t)blockIdx.x * (64 * D));
  #pragma unroll
  for (int it = 0; it < 24; ++it) {
    int cid = it * 512 + tid;                 // 0..12287
    int row = cid / (D / 4);
    int c4  = cid - row * (D / 4);
    float4 v = x4[cid];
    bf16x4 h = { (__bf16)v.x, (__bf16)v.y, (__bf16)v.z, (__bf16)v.w };
    *reinterpret_cast<bf16x4*>(smem + row * LDS_ROW_BYTES + c4 * 8) = h;
  }
  __syncthreads();

  const int lane = tid & 63;
  const int wv = tid >> 6;                    // 0..7
  const int wm = wv >> 2;                     // 0..1 row half
  const int wn = wv & 3;                      // 0..3 n-tile group
  const int lo = lane & 15;
  const int kg = lane >> 4;

  const char* abase0 = smem + (wm * 32 +  0 + lo) * LDS_ROW_BYTES + kg * 16;
  const char* abase1 = smem + (wm * 32 + 16 + lo) * LDS_ROW_BYTES + kg * 16;

  float sacc[2][4] = {};

  for (int nti = 0; nti < 3; ++nti) {
    const int nbase = (wn + nti * 4) * 64;
    f32x4 acc[2][4];
    #pragma unroll
    for (int mf = 0; mf < 2; ++mf)
      #pragma unroll
      for (int nf = 0; nf < 4; ++nf)
        acc[mf][nf] = (f32x4){0.f, 0.f, 0.f, 0.f};

    const bf16x8* bp0 = reinterpret_cast<const bf16x8*>(w1t + (size_t)(nbase +  0 + lo) * D + kg * 8);
    const bf16x8* bp1 = reinterpret_cast<const bf16x8*>(w1t + (size_t)(nbase + 16 + lo) * D + kg * 8);
    const bf16x8* bp2 = reinterpret_cast<const bf16x8*>(w1t + (size_t)(nbase + 32 + lo) * D + kg * 8);
    const bf16x8* bp3 = reinterpret_cast<const bf16x8*>(w1t + (size_t)(nbase + 48 + lo) * D + kg * 8);

    #pragma unroll
    for (int s = 0; s < 24; ++s) {            // K = 24 * 32
      bf16x8 a0 = *reinterpret_cast<const bf16x8*>(abase0 + s * 64);
      bf16x8 a1 = *reinterpret_cast<const bf16x8*>(abase1 + s * 64);
      bf16x8 f0 = bp0[s * 4];
      bf16x8 f1 = bp1[s * 4];
      bf16x8 f2 = bp2[s * 4];
      bf16x8 f3 = bp3[s * 4];
      acc[0][0] = __builtin_amdgcn_mfma_f32_16x16x32_bf16(a0, f0, acc[0][0], 0, 0, 0);
      acc[1][0] = __builtin_amdgcn_mfma_f32_16x16x32_bf16(a1, f0, acc[1][0], 0, 0, 0);
      acc[0][1] = __builtin_amdgcn_mfma_f32_16x16x32_bf16(a0, f1, acc[0][1], 0, 0, 0);
      acc[1][1] = __builtin_amdgcn_mfma_f32_16x16x32_bf16(a1, f1, acc[1][1], 0, 0, 0);
      acc[0][2] = __builtin_amdgcn_mfma_f32_16x16x32_bf16(a0, f2, acc[0][2], 0, 0, 0);
      acc[1][2] = __builtin_amdgcn_mfma_f32_16x16x32_bf16(a1, f2, acc[1][2], 0, 0, 0);
      acc[0][3] = __builtin_amdgcn_mfma_f32_16x16x32_bf16(a0, f3, acc[0][3], 0, 0, 0);
      acc[1][3] = __builtin_amdgcn_mfma_f32_16x16x32_bf16(a1, f3, acc[1][3], 0, 0, 0);
    }

    // epilogue: tanh + w2 dot (fast tanh via exp)
    #pragma unroll
    for (int nf = 0; nf < 4; ++nf) {
      int n = nbase + nf * 16 + lo;
      float b1v = b1[n];
      float w2v = w2[n];
      #pragma unroll
      for (int mf = 0; mf < 2; ++mf)
        #pragma unroll
        for (int r = 0; r < 4; ++r) {
          float z = acc[mf][nf][r] + b1v;
          float e = __expf(2.f * z);
          float th = 1.f - 2.f / (e + 1.f);
          sacc[mf][r] += w2v * th;
        }
    }
  }

  // reduce across the 16 lanes (lo) that hold different n columns
  #pragma unroll
  for (int mf = 0; mf < 2; ++mf)
    #pragma unroll
    for (int r = 0; r < 4; ++r) {
      float v = sacc[mf][r];
      v += __shfl_xor(v, 1);
      v += __shfl_xor(v, 2);
      v += __shfl_xor(v, 4);
      v += __shfl_xor(v, 8);
      sacc[mf][r] = v;
    }
  if (lo == 0) {
    int rowb = blockIdx.x * 64 + wm * 32;
    #pragma unroll
    for (int mf = 0; mf < 2; ++mf)
      #pragma unroll
      for (int r = 0; r < 4; ++r)
        atomicAdd(&scores[rowb + mf * 16 + kg * 4 + r], sacc[mf][r]);
  }
}

// ---------------- K5: masked softmax over L=128 ----------------
__global__ void k_probs(const float* __restrict__ scores, const float* __restrict__ mask,
                        float* __restrict__ probs) {
  int bs = blockIdx.x, t = threadIdx.x;       // 128 threads
  __shared__ float sc[L];
  float s = scores[bs * L + t] + (1.f - mask[bs * L + t]) * -10000.f;
  sc[t] = s;
  __syncthreads();
  float mx = -1e30f;
  #pragma unroll 8
  for (int l = 0; l < L; ++l) mx = fmaxf(mx, sc[l]);
  float sum = 0.f;
  #pragma unroll 8
  for (int l = 0; l < L; ++l) sum += __expf(sc[l] - mx);
  probs[bs * L + t] = __expf(s - mx) / sum;
}

// ---------------- K6: final_sent = probs . x ----------------
__global__ void k_final(const float* __restrict__ x, const float* __restrict__ probs,
                        float* __restrict__ out) {
  int bs = blockIdx.x >> 2, chunk = blockIdx.x & 3;
  int d = chunk * 192 + threadIdx.x;          // 192 threads
  __shared__ float p[L];
  if (threadIdx.x < L) p[threadIdx.x] = probs[bs * L + threadIdx.x];
  __syncthreads();
  float acc = 0.f;
  const float* xp = x + (size_t)bs * L * D + d;
  #pragma unroll 4
  for (int l = 0; l < L; ++l) acc += p[l] * xp[(size_t)l * D];
  out[bs * D + d] = acc;
}

// ---------------- launch ----------------
extern "C" void kernel_launch(void* const* d_in, const int* in_sizes, int n_in,
                              void* d_out, int out_size, void* d_ws, size_t ws_size,
                              hipStream_t stream) {
  const float* x    = (const float*)d_in[0];
  const float* xcls = (const float*)d_in[1];
  const float* mask = (const float*)d_in[2];
  const float* w1   = (const float*)d_in[3];
  const float* b1   = (const float*)d_in[4];
  const float* w2   = (const float*)d_in[5];
  // d_in[6] = b2: softmax is shift-invariant, b2 cancels exactly.
  const int* pairs  = (const int*)d_in[7];
  const int* pnum   = (const int*)d_in[8];

  float* out_final = (float*)d_out;                      // (8,32,768)
  float* out_cls   = (float*)d_out + (size_t)BS * S * D; // (8,32,32,768)

  __bf16* w1t   = (__bf16*)d_ws;                         // 589824*2 B
  float* scores = (float*)((char*)d_ws + (size_t)D * D * 2);
  float* probs  = scores + BS * S * L;

  {
    int n = (BS * S * S * D) / 4;
    k_zero<<<(n + 255) / 256, 256, 0, stream>>>((float4*)out_cls, n);
  }
  {
    int n = (BS * S * L) / 4;
    k_zero<<<(n + 255) / 256, 256, 0, stream>>>((float4*)scores, n);
  }
  k_w1t<<<(D * D) / 256, 256, 0, stream>>>(w1, w1t);
  k_scatter<<<dim3(P, BS), D / 4, 0, stream>>>((const float4*)xcls, pairs, pnum, (float4*)out_cls);

  hipFuncSetAttribute((const void*)k_scores, hipFuncAttributeMaxDynamicSharedMemorySize, LDS_BYTES);
  k_scores<<<(BS * S * L) / 64, 512, LDS_BYTES, stream>>>(x, w1t, b1, w2, scores);

  k_probs<<<BS * S, L, 0, stream>>>(scores, mask, probs);
  k_final<<<BS * S * 4, 192, 0, stream>>>(x, probs, out_final);
}

// Round 2
// 270.571 us; speedup vs baseline: 1.3909x; 1.3909x over previous
//
#include <hip/hip_runtime.h>
#include <hip/hip_bf16.h>
#include <stdint.h>

#define BS 8
#define S  32
#define L  128
#define D  768
#define P  496

typedef float  f32x4  __attribute__((ext_vector_type(4)));
typedef __bf16 bf16x8 __attribute__((ext_vector_type(8)));
typedef __bf16 bf16x4 __attribute__((ext_vector_type(4)));

// ---------------- K1: zero float4s ----------------
__global__ void k_zero(float4* __restrict__ p, int n) {
  int i = blockIdx.x * blockDim.x + threadIdx.x;
  if (i < n) p[i] = make_float4(0.f, 0.f, 0.f, 0.f);
}

// ---------------- K2: W1[d][h] f32 -> W1T[h][d] bf16 ----------------
__global__ void k_w1t(const float* __restrict__ w1, __bf16* __restrict__ w1t) {
  int idx = blockIdx.x * 256 + threadIdx.x;   // idx = h*D + d  (writes coalesced)
  int h = idx / D, d = idx - h * D;
  w1t[idx] = (__bf16)w1[d * D + h];
}

// ---------------- K2b: x f32 -> bf16 ----------------
__global__ void k_cvt(const float4* __restrict__ x, bf16x4* __restrict__ xb, int n4) {
  for (int i = blockIdx.x * blockDim.x + threadIdx.x; i < n4; i += gridDim.x * blockDim.x) {
    float4 v = x[i];
    bf16x4 h = { (__bf16)v.x, (__bf16)v.y, (__bf16)v.z, (__bf16)v.w };
    xb[i] = h;
  }
}

// ---------------- K3: scatter x_cls rows into cls output ----------------
__global__ void k_scatter(const float4* __restrict__ xcls, const int* __restrict__ pairs,
                          const int* __restrict__ pnum, float4* __restrict__ outc) {
  int p = blockIdx.x, b = blockIdx.y;
  if (p >= pnum[b]) return;
  int i = pairs[(b * P + p) * 2 + 0];
  int j = pairs[(b * P + p) * 2 + 1];
  const float4* src = xcls + (size_t)(b * P + p) * (D / 4);
  float4*       dst = outc + (size_t)((b * S + i) * S + j) * (D / 4);
  dst[threadIdx.x] = src[threadIdx.x];
}

// ---------------- K4: scores GEMM (m97 structure) ----------------
// 128x128 tile, BK=64 (128B/row), 4 waves (2x2), dbuf LDS via global_load_lds,
// XOR-swizzle chunk ^= row&7 applied on the GLOBAL source (LDS dest linear),
// ds_read_b128 with matching swizzle. Epilogue: tanh + w2-dot -> atomicAdd.
#define GEMM_LDS 65536   // 2 bufs x (A 16KB + B 16KB)

__global__ __launch_bounds__(256) void k_gemm_scores(
    const __bf16* __restrict__ xb, const __bf16* __restrict__ w1t,
    const float* __restrict__ b1, const float* __restrict__ w2,
    float* __restrict__ scores)
{
  extern __shared__ char smem[];

  // XCD-aware swizzle: nwg = 1536, 1536 % 8 == 0, chunk = 192
  int bid = blockIdx.x;
  int swz = (bid & 7) * 192 + (bid >> 3);
  int bm = swz / 6, bn = swz - 6 * bm;        // 256 M-tiles x 6 N-tiles

  const int tid  = threadIdx.x;
  const int lane = tid & 63, wv = tid >> 6;   // 4 waves
  const int wm = wv >> 1, wn = wv & 1;        // 2x2 -> 64x64 per wave
  const int lo = lane & 15, kg = lane >> 4;

  // staging source addresses (per-lane, pre-swizzled): o = inst*4096 + tid*16
  const char* Ag[4];
  const char* Bg[4];
  #pragma unroll
  for (int inst = 0; inst < 4; ++inst) {
    int o  = inst * 4096 + tid * 16;
    int r  = o >> 7;                          // tile row 0..127
    int c2 = (o >> 4) & 7;                    // 16B chunk in 128B row
    int sc = c2 ^ (r & 7);                    // inverse swizzle on source
    Ag[inst] = (const char*)xb  + (size_t)(bm * 128 + r) * (D * 2) + sc * 16;
    Bg[inst] = (const char*)w1t + (size_t)(bn * 128 + r) * (D * 2) + sc * 16;
  }

  auto STAGE = [&](int buf, int t) {
    char* la = smem + buf * 32768 + wv * 1024;
    char* lb = la + 16384;
    const size_t koff = (size_t)t * 128;
    #pragma unroll
    for (int inst = 0; inst < 4; ++inst) {
      __builtin_amdgcn_global_load_lds(
          (const __attribute__((address_space(1))) void*)(Ag[inst] + koff),
          (__attribute__((address_space(3))) void*)(la + inst * 4096), 16, 0, 0);
      __builtin_amdgcn_global_load_lds(
          (const __attribute__((address_space(1))) void*)(Bg[inst] + koff),
          (__attribute__((address_space(3))) void*)(lb + inst * 4096), 16, 0, 0);
    }
  };

  f32x4 acc[4][4];
  #pragma unroll
  for (int mf = 0; mf < 4; ++mf)
    #pragma unroll
    for (int nf = 0; nf < 4; ++nf)
      acc[mf][nf] = (f32x4){0.f, 0.f, 0.f, 0.f};

  STAGE(0, 0);
  __syncthreads();

  for (int t = 0; t < 12; ++t) {
    const int cur = t & 1;
    if (t < 11) STAGE(cur ^ 1, t + 1);

    const char* As = smem + cur * 32768;
    const char* Bs = As + 16384;
    bf16x8 a[4][2], b[4][2];
    #pragma unroll
    for (int mf = 0; mf < 4; ++mf)
      #pragma unroll
      for (int kk = 0; kk < 2; ++kk)
        a[mf][kk] = *(const bf16x8*)(As + (wm * 64 + mf * 16 + lo) * 128
                                        + (((kk * 4 + kg) ^ (lo & 7)) * 16));
    #pragma unroll
    for (int nf = 0; nf < 4; ++nf)
      #pragma unroll
      for (int kk = 0; kk < 2; ++kk)
        b[nf][kk] = *(const bf16x8*)(Bs + (wn * 64 + nf * 16 + lo) * 128
                                        + (((kk * 4 + kg) ^ (lo & 7)) * 16));
    #pragma unroll
    for (int kk = 0; kk < 2; ++kk)
      #pragma unroll
      for (int mf = 0; mf < 4; ++mf)
        #pragma unroll
        for (int nf = 0; nf < 4; ++nf)
          acc[mf][nf] = __builtin_amdgcn_mfma_f32_16x16x32_bf16(a[mf][kk], b[nf][kk], acc[mf][nf], 0, 0, 0);

    __syncthreads();
  }

  // epilogue: tanh + w2 dot over this block's 128 cols, reduce, atomicAdd
  float part[4][4];
  #pragma unroll
  for (int mf = 0; mf < 4; ++mf)
    #pragma unroll
    for (int r = 0; r < 4; ++r) part[mf][r] = 0.f;

  #pragma unroll
  for (int nf = 0; nf < 4; ++nf) {
    int n = bn * 128 + wn * 64 + nf * 16 + lo;
    float b1v = b1[n], w2v = w2[n];
    #pragma unroll
    for (int mf = 0; mf < 4; ++mf)
      #pragma unroll
      for (int r = 0; r < 4; ++r) {
        float z = acc[mf][nf][r] + b1v;
        float e = __expf(2.f * z);
        part[mf][r] += w2v * (1.f - 2.f / (e + 1.f));
      }
  }
  #pragma unroll
  for (int mf = 0; mf < 4; ++mf)
    #pragma unroll
    for (int r = 0; r < 4; ++r) {
      float v = part[mf][r];
      v += __shfl_xor(v, 1);
      v += __shfl_xor(v, 2);
      v += __shfl_xor(v, 4);
      v += __shfl_xor(v, 8);
      part[mf][r] = v;
    }
  if (lo == 0) {
    int rowb = bm * 128 + wm * 64;
    #pragma unroll
    for (int mf = 0; mf < 4; ++mf)
      #pragma unroll
      for (int r = 0; r < 4; ++r)
        atomicAdd(&scores[rowb + mf * 16 + kg * 4 + r], part[mf][r]);
  }
}

// ---------------- K5: masked softmax over L=128 ----------------
__global__ void k_probs(const float* __restrict__ scores, const float* __restrict__ mask,
                        float* __restrict__ probs) {
  int bs = blockIdx.x, t = threadIdx.x;       // 128 threads
  __shared__ float sc[L];
  float s = scores[bs * L + t] + (1.f - mask[bs * L + t]) * -10000.f;
  sc[t] = s;
  __syncthreads();
  float mx = -1e30f;
  #pragma unroll 8
  for (int l = 0; l < L; ++l) mx = fmaxf(mx, sc[l]);
  float sum = 0.f;
  #pragma unroll 8
  for (int l = 0; l < L; ++l) sum += __expf(sc[l] - mx);
  probs[bs * L + t] = __expf(s - mx) / sum;
}

// ---------------- K6: final_sent = probs . x (bf16 copy) ----------------
__global__ void k_final(const __bf16* __restrict__ xb, const float* __restrict__ probs,
                        float* __restrict__ out) {
  int bs = blockIdx.x;                        // 256 blocks
  int t  = threadIdx.x;                       // 192 threads, 4 d's each
  __shared__ float p[L];
  if (t < L) p[t] = probs[bs * L + t];
  __syncthreads();
  const bf16x4* xp = (const bf16x4*)(xb + (size_t)bs * L * D) + t;
  float4 acc = make_float4(0.f, 0.f, 0.f, 0.f);
  #pragma unroll 4
  for (int l = 0; l < L; ++l) {
    bf16x4 v = xp[(size_t)l * (D / 4)];
    float pl = p[l];
    acc.x += pl * (float)v[0];
    acc.y += pl * (float)v[1];
    acc.z += pl * (float)v[2];
    acc.w += pl * (float)v[3];
  }
  ((float4*)(out + (size_t)bs * D))[t] = acc;
}

// ---------------- launch ----------------
extern "C" void kernel_launch(void* const* d_in, const int* in_sizes, int n_in,
                              void* d_out, int out_size, void* d_ws, size_t ws_size,
                              hipStream_t stream) {
  const float* x    = (const float*)d_in[0];
  const float* xcls = (const float*)d_in[1];
  const float* mask = (const float*)d_in[2];
  const float* w1   = (const float*)d_in[3];
  const float* b1   = (const float*)d_in[4];
  const float* w2   = (const float*)d_in[5];
  // d_in[6] = b2: softmax is shift-invariant, b2 cancels exactly.
  const int* pairs  = (const int*)d_in[7];
  const int* pnum   = (const int*)d_in[8];

  float* out_final = (float*)d_out;                      // (8,32,768)
  float* out_cls   = (float*)d_out + (size_t)BS * S * D; // (8,32,32,768)

  // workspace layout
  __bf16* xb    = (__bf16*)d_ws;                                  // 48 MB
  __bf16* w1t   = (__bf16*)((char*)d_ws + (size_t)BS * S * L * D * 2);
  float* scores = (float*)((char*)w1t + (size_t)D * D * 2);
  float* probs  = scores + BS * S * L;

  {
    int n = (BS * S * S * D) / 4;
    k_zero<<<(n + 255) / 256, 256, 0, stream>>>((float4*)out_cls, n);
  }
  {
    int n = (BS * S * L) / 4;
    k_zero<<<(n + 255) / 256, 256, 0, stream>>>((float4*)scores, n);
  }
  k_w1t<<<(D * D) / 256, 256, 0, stream>>>(w1, w1t);
  k_cvt<<<2048, 256, 0, stream>>>((const float4*)x, (bf16x4*)xb, (BS * S * L * D) / 4);
  k_scatter<<<dim3(P, BS), D / 4, 0, stream>>>((const float4*)xcls, pairs, pnum, (float4*)out_cls);

  hipFuncSetAttribute((const void*)k_gemm_scores, hipFuncAttributeMaxDynamicSharedMemorySize, GEMM_LDS);
  k_gemm_scores<<<(32768 / 128) * (D / 128), 256, GEMM_LDS, stream>>>(xb, w1t, b1, w2, scores);

  k_probs<<<BS * S, L, 0, stream>>>(scores, mask, probs);
  k_final<<<BS * S, 192, 0, stream>>>(xb, probs, out_final);
}